// Round 7
// baseline (355.070 us; speedup 1.0000x reference)
//
#include <hip/hip_runtime.h>
#include <math.h>

#define N_OBS_C 2000000
#define N_REFL_C 250000
#define N_IMG_C 2000
#define MC_C 32
#define HID 64
#define NSLOT 16
#define LOG2PI_F 1.8378770664093453f

// ---------------- workspace layout (bytes) ----------------
// [0,64)           accs: 8 doubles (kl, llmax, 6 pearson)
// [64,256064)      img_ll_part [2000][2][NSLOT] float   (zeroed each launch)
// [262144,270144)  op_idx [2000] int
// [524288,...)     sq [250000] float
// [1572864,...)    img_pre [2000][64] float
// [2097152,...)    zT [250000][32] float (32MB)
// [34603008,...)   ipred_mean [2000000][2] float (16MB)
// [52428800,...)   params [2000000] float4 (32MB)

__device__ __forceinline__ float softplusf(float x) {
    return (x > 20.f) ? x : log1pf(expf(x));
}

// ---- K1: per-reflection: sq = softplus(q_scale_raw), KL partial, zT table ----
__global__ __launch_bounds__(256) void k_refl(const float* __restrict__ q_loc,
                                              const float* __restrict__ q_scale_raw,
                                              const float* __restrict__ zeps,
                                              float* __restrict__ sq,
                                              float* __restrict__ zT,
                                              double* __restrict__ kl_sum) {
    int r = blockIdx.x * 256 + threadIdx.x;
    double kl = 0.0;
    if (r < N_REFL_C) {
        float ql = q_loc[r];
        float sp = softplusf(q_scale_raw[r]);
        sq[r] = sp;
        kl = (double)(-logf(sp) + 0.5f * (sp * sp + ql * ql) - 0.5f);
        float z[MC_C];
#pragma unroll
        for (int m = 0; m < MC_C; ++m)
            z[m] = fmaf(sp, zeps[(size_t)m * N_REFL_C + r], ql);
        float4* outp = (float4*)(zT + (size_t)r * MC_C);
#pragma unroll
        for (int q = 0; q < MC_C / 4; ++q)
            outp[q] = make_float4(z[4 * q], z[4 * q + 1], z[4 * q + 2], z[4 * q + 3]);
    }
    for (int o = 32; o > 0; o >>= 1) kl += __shfl_xor(kl, o);
    __shared__ double skl[4];
    int lane = threadIdx.x & 63, w = threadIdx.x >> 6;
    if (lane == 0) skl[w] = kl;
    __syncthreads();
    if (threadIdx.x == 0) atomicAdd(kl_sum, skl[0] + skl[1] + skl[2] + skl[3]);
}

// ---- K1b: per-image precompute ----
__global__ __launch_bounds__(64) void k_imgpre(const float* __restrict__ img_emb,
                                               const float* __restrict__ W1,
                                               const float* __restrict__ b1,
                                               float* __restrict__ img_pre) {
    int g = blockIdx.x;
    int j = threadIdx.x;
    float acc = b1[j];
#pragma unroll
    for (int e = 0; e < 32; ++e)
        acc = fmaf(img_emb[g * 32 + e], W1[(12 + e) * HID + j], acc);
    img_pre[g * HID + j] = acc;
}

// ---- K2a: MLP, 2 obs per thread; weights staged in LDS ----
__global__ __launch_bounds__(256) void k_mlp(const float* __restrict__ I,
                                             const float* __restrict__ SigI,
                                             const int* __restrict__ image_id,
                                             const float* __restrict__ metadata,
                                             const float* __restrict__ wavelength,
                                             const float* __restrict__ dHKL,
                                             const int* __restrict__ refl_ids,
                                             const float* __restrict__ q_loc,
                                             const float* __restrict__ W1,
                                             const float* __restrict__ W2,
                                             const float* __restrict__ b2,
                                             const float* __restrict__ sq,
                                             const float* __restrict__ img_pre,
                                             float4* __restrict__ params) {
    __shared__ float sW1[12 * HID];          // rows 0..11 of W1
    __shared__ float sW2a[HID], sW2b[HID];   // W2 columns, deinterleaved
    for (int t = threadIdx.x; t < 12 * HID; t += 256) sW1[t] = W1[t];
    if (threadIdx.x < HID) {
        sW2a[threadIdx.x] = W2[threadIdx.x * 2 + 0];
        sW2b[threadIdx.x] = W2[threadIdx.x * 2 + 1];
    }
    __syncthreads();

    int n0 = blockIdx.x * 512 + threadIdx.x;
    int n1 = n0 + 256;
    bool a0 = (n0 < N_OBS_C), a1 = (n1 < N_OBS_C);
    int m0 = a0 ? n0 : (N_OBS_C - 1);
    int m1 = a1 ? n1 : (N_OBS_C - 1);

    float f0[12], f1[12];
    f0[2] = I[m0];   f1[2] = I[m1];
    f0[3] = SigI[m0]; f1[3] = SigI[m1];
#pragma unroll
    for (int i = 0; i < 6; ++i) {
        f0[4 + i] = metadata[(size_t)m0 * 6 + i];
        f1[4 + i] = metadata[(size_t)m1 * 6 + i];
    }
    f0[10] = wavelength[m0]; f1[10] = wavelength[m1];
    float dh0 = dHKL[m0], dh1 = dHKL[m1];
    f0[11] = 1.0f / (dh0 * dh0);
    f1[11] = 1.0f / (dh1 * dh1);
    int g0 = image_id[m0], g1 = image_id[m1];
    int r00 = refl_ids[m0], r01 = refl_ids[N_OBS_C + m0];
    int r10 = refl_ids[m1], r11 = refl_ids[N_OBS_C + m1];
    float qa0 = q_loc[r00], sa0 = sq[r00];
    float qb0 = q_loc[r01], sb0 = sq[r01];
    float qa1 = q_loc[r10], sa1 = sq[r10];
    float qb1 = q_loc[r11], sb1 = sq[r11];
    const float* ip0 = img_pre + (size_t)g0 * HID;
    const float* ip1 = img_pre + (size_t)g1 * HID;

    float bb0 = b2[0], bb1 = b2[1];
    float la00 = bb0, la01 = bb1, lb00 = bb0, lb01 = bb1;
    float la10 = bb0, la11 = bb1, lb10 = bb0, lb11 = bb1;

#pragma unroll 1
    for (int jt = 0; jt < HID; jt += 8) {
        float acc0[8], acc1[8];
        {
            float4 p0a = *(const float4*)&ip0[jt];
            float4 p0b = *(const float4*)&ip0[jt + 4];
            float4 p1a = *(const float4*)&ip1[jt];
            float4 p1b = *(const float4*)&ip1[jt + 4];
            acc0[0] = p0a.x; acc0[1] = p0a.y; acc0[2] = p0a.z; acc0[3] = p0a.w;
            acc0[4] = p0b.x; acc0[5] = p0b.y; acc0[6] = p0b.z; acc0[7] = p0b.w;
            acc1[0] = p1a.x; acc1[1] = p1a.y; acc1[2] = p1a.z; acc1[3] = p1a.w;
            acc1[4] = p1b.x; acc1[5] = p1b.y; acc1[6] = p1b.z; acc1[7] = p1b.w;
        }
#pragma unroll
        for (int i = 2; i < 12; ++i) {
            float4 wa = *(const float4*)&sW1[i * HID + jt];
            float4 wb = *(const float4*)&sW1[i * HID + jt + 4];
            float u0 = f0[i], u1 = f1[i];
            acc0[0] = fmaf(u0, wa.x, acc0[0]); acc1[0] = fmaf(u1, wa.x, acc1[0]);
            acc0[1] = fmaf(u0, wa.y, acc0[1]); acc1[1] = fmaf(u1, wa.y, acc1[1]);
            acc0[2] = fmaf(u0, wa.z, acc0[2]); acc1[2] = fmaf(u1, wa.z, acc1[2]);
            acc0[3] = fmaf(u0, wa.w, acc0[3]); acc1[3] = fmaf(u1, wa.w, acc1[3]);
            acc0[4] = fmaf(u0, wb.x, acc0[4]); acc1[4] = fmaf(u1, wb.x, acc1[4]);
            acc0[5] = fmaf(u0, wb.y, acc0[5]); acc1[5] = fmaf(u1, wb.y, acc1[5]);
            acc0[6] = fmaf(u0, wb.z, acc0[6]); acc1[6] = fmaf(u1, wb.z, acc1[6]);
            acc0[7] = fmaf(u0, wb.w, acc0[7]); acc1[7] = fmaf(u1, wb.w, acc1[7]);
        }
        float4 w0a = *(const float4*)&sW1[jt];
        float4 w0b = *(const float4*)&sW1[jt + 4];
        float4 w1a = *(const float4*)&sW1[HID + jt];
        float4 w1b = *(const float4*)&sW1[HID + jt + 4];
        float w0r[8] = {w0a.x, w0a.y, w0a.z, w0a.w, w0b.x, w0b.y, w0b.z, w0b.w};
        float w1r[8] = {w1a.x, w1a.y, w1a.z, w1a.w, w1b.x, w1b.y, w1b.z, w1b.w};
        float4 va4a = *(const float4*)&sW2a[jt];
        float4 va4b = *(const float4*)&sW2a[jt + 4];
        float4 vb4a = *(const float4*)&sW2b[jt];
        float4 vb4b = *(const float4*)&sW2b[jt + 4];
        float va[8] = {va4a.x, va4a.y, va4a.z, va4a.w, va4b.x, va4b.y, va4b.z, va4b.w};
        float vb[8] = {vb4a.x, vb4a.y, vb4a.z, vb4a.w, vb4b.x, vb4b.y, vb4b.z, vb4b.w};
#pragma unroll
        for (int jj = 0; jj < 8; ++jj) {
            float ha0 = fmaxf(fmaf(qa0, w0r[jj], fmaf(sa0, w1r[jj], acc0[jj])), 0.f);
            la00 = fmaf(ha0, va[jj], la00);
            la01 = fmaf(ha0, vb[jj], la01);
            float hb0 = fmaxf(fmaf(qb0, w0r[jj], fmaf(sb0, w1r[jj], acc0[jj])), 0.f);
            lb00 = fmaf(hb0, va[jj], lb00);
            lb01 = fmaf(hb0, vb[jj], lb01);
            float ha1 = fmaxf(fmaf(qa1, w0r[jj], fmaf(sa1, w1r[jj], acc1[jj])), 0.f);
            la10 = fmaf(ha1, va[jj], la10);
            la11 = fmaf(ha1, vb[jj], la11);
            float hb1 = fmaxf(fmaf(qb1, w0r[jj], fmaf(sb1, w1r[jj], acc1[jj])), 0.f);
            lb10 = fmaf(hb1, va[jj], lb10);
            lb11 = fmaf(hb1, vb[jj], lb11);
        }
    }

    if (a0) params[n0] = make_float4(la00, softplusf(la01), lb00, softplusf(lb01));
    if (a1) params[n1] = make_float4(la10, softplusf(la11), lb10, softplusf(lb11));
}

// ---- K2b: MC likelihood + ipred; 8 lanes/obs, block combine, slotted atomics ----
// block 256 = 32 obs; grid = 2M/32 = 62500 exact.
__global__ __launch_bounds__(256) void k_mc(const float* __restrict__ I,
                                            const float* __restrict__ SigI,
                                            const int* __restrict__ image_id,
                                            const int* __restrict__ refl_ids,
                                            const float4* __restrict__ params,
                                            const float* __restrict__ seps,
                                            const float* __restrict__ zT,
                                            float* __restrict__ img_ll_part,
                                            float* __restrict__ ipred_mean) {
    int t = threadIdx.x;
    int grp = t >> 3;            // obs slot in block (0..31)
    int m4 = t & 7;              // sample quartet
    int n = blockIdx.x * 32 + grp;

    float In = I[n];
    float Sn = SigI[n];
    int g = image_id[n];
    int rid0 = refl_ids[n];
    int rid1 = refl_ids[N_OBS_C + n];
    float4 pp = params[n];

    float4 ss = *(const float4*)&seps[(size_t)n * MC_C + m4 * 4];
    float4 z0 = *(const float4*)&zT[(size_t)rid0 * MC_C + m4 * 4];
    float4 z1 = *(const float4*)&zT[(size_t)rid1 * MC_C + m4 * 4];

    float rsig = 1.0f / Sn;
    float mnIr = -In * rsig;

    float sd20 = 0.f, sip0 = 0.f, sd21 = 0.f, sip1 = 0.f;
#define MCSTEP(zc0, zc1, sc_)                              \
    {                                                      \
        float sc0 = fmaf(pp.y, sc_, pp.x);                 \
        float ip0 = zc0 * sc0;                             \
        float d0 = fmaf(ip0, rsig, mnIr);                  \
        sd20 = fmaf(d0, d0, sd20);                         \
        sip0 += ip0;                                       \
        float sc1 = fmaf(pp.w, sc_, pp.z);                 \
        float ip1 = zc1 * sc1;                             \
        float d1 = fmaf(ip1, rsig, mnIr);                  \
        sd21 = fmaf(d1, d1, sd21);                         \
        sip1 += ip1;                                       \
    }
    MCSTEP(z0.x, z1.x, ss.x)
    MCSTEP(z0.y, z1.y, ss.y)
    MCSTEP(z0.z, z1.z, ss.z)
    MCSTEP(z0.w, z1.w, ss.w)
#undef MCSTEP

    // reduce over the 8-lane group
#pragma unroll
    for (int o = 4; o > 0; o >>= 1) {
        sd20 += __shfl_xor(sd20, o);
        sd21 += __shfl_xor(sd21, o);
        sip0 += __shfl_xor(sip0, o);
        sip1 += __shfl_xor(sip1, o);
    }

    __shared__ float s0[32], s1[32];
    __shared__ int sg[32];
    if (m4 == 0) {
        float logS32 = 32.f * logf(Sn) + 16.f * LOG2PI_F;
        s0[grp] = -0.5f * sd20 - logS32;
        s1[grp] = -0.5f * sd21 - logS32;
        sg[grp] = g;
        float2* ip2 = (float2*)(ipred_mean + (size_t)n * 2);
        *ip2 = make_float2(sip0 * (1.0f / 32.0f), sip1 * (1.0f / 32.0f));
    }
    __syncthreads();
    if (t == 0) {
        int slot = blockIdx.x & (NSLOT - 1);
        int g0 = sg[0];
        bool same = true;
        float a0 = 0.f, a1 = 0.f;
#pragma unroll
        for (int s = 0; s < 32; ++s) {
            same = same && (sg[s] == g0);
            a0 += s0[s];
            a1 += s1[s];
        }
        if (same) {
            atomicAdd(&img_ll_part[(g0 * 2 + 0) * NSLOT + slot], a0);
            atomicAdd(&img_ll_part[(g0 * 2 + 1) * NSLOT + slot], a1);
        } else {
            for (int s = 0; s < 32; ++s) {
                atomicAdd(&img_ll_part[(sg[s] * 2 + 0) * NSLOT + slot], s0[s]);
                atomicAdd(&img_ll_part[(sg[s] * 2 + 1) * NSLOT + slot], s1[s]);
            }
        }
    }
}

// ---- K3: per-image slot-sum + argmax + sum of ll_max ----
__global__ __launch_bounds__(256) void k_img(const float* __restrict__ img_ll_part,
                                             int* __restrict__ op_idx,
                                             double* __restrict__ llmax_sum) {
    int g = blockIdx.x * 256 + threadIdx.x;
    double v = 0.0;
    if (g < N_IMG_C) {
        float v0 = 0.f, v1 = 0.f;
#pragma unroll
        for (int s = 0; s < NSLOT; ++s) {
            v0 += img_ll_part[(g * 2 + 0) * NSLOT + s];
            v1 += img_ll_part[(g * 2 + 1) * NSLOT + s];
        }
        v0 *= (1.0f / 32.0f);
        v1 *= (1.0f / 32.0f);
        op_idx[g] = (v1 > v0) ? 1 : 0;
        v = (double)fmaxf(v0, v1);
    }
    for (int o = 32; o > 0; o >>= 1) v += __shfl_xor(v, o);
    __shared__ double sv[4];
    int lane = threadIdx.x & 63, w = threadIdx.x >> 6;
    if (lane == 0) sv[w] = v;
    __syncthreads();
    if (threadIdx.x == 0) atomicAdd(llmax_sum, sv[0] + sv[1] + sv[2] + sv[3]);
}

// ---- K4: weighted pearson moment sums ----
__global__ __launch_bounds__(256) void k_pearson(const float* __restrict__ I,
                                                 const float* __restrict__ SigI,
                                                 const int* __restrict__ image_id,
                                                 const float* __restrict__ ipred_mean,
                                                 const int* __restrict__ op_idx,
                                                 double* __restrict__ acc) {
    int n = blockIdx.x * 256 + threadIdx.x;
    double s[6] = {0, 0, 0, 0, 0, 0};
    if (n < N_OBS_C) {
        float x = I[n];
        float sg = SigI[n];
        float w = 1.0f / (sg * sg);
        int g = image_id[n];
        int o = op_idx[g];
        float y = ipred_mean[(size_t)n * 2 + o];
        double dw = (double)w, dx = (double)x, dy = (double)y;
        s[0] = dw;
        s[1] = dw * dx;
        s[2] = dw * dy;
        s[3] = dw * dx * dx;
        s[4] = dw * dy * dy;
        s[5] = dw * dx * dy;
    }
#pragma unroll
    for (int k = 0; k < 6; ++k)
        for (int o = 32; o > 0; o >>= 1) s[k] += __shfl_xor(s[k], o);
    __shared__ double red[4][6];
    int lane = threadIdx.x & 63, w = threadIdx.x >> 6;
    if (lane == 0) {
#pragma unroll
        for (int k = 0; k < 6; ++k) red[w][k] = s[k];
    }
    __syncthreads();
    if (threadIdx.x < 6) {
        double t = red[0][threadIdx.x] + red[1][threadIdx.x] +
                   red[2][threadIdx.x] + red[3][threadIdx.x];
        atomicAdd(&acc[threadIdx.x], t);
    }
}

// ---- K5: finalize ----
__global__ void k_final(const double* __restrict__ accs, float* __restrict__ out) {
    double kl = accs[0] / (double)N_REFL_C;
    double elbo = -(accs[1] / (double)N_IMG_C) + 1.0 * kl;
    double W = accs[2], Sx = accs[3], Sy = accs[4];
    double Sxx = accs[5], Syy = accs[6], Sxy = accs[7];
    double z = 1.0 / W;
    double mx = z * Sx, my = z * Sy;
    double cxy = z * Sxy - mx * my;
    double cx = z * Sxx - mx * mx;
    double cy = z * Syy - my * my;
    double cc = cxy / sqrt(cx * cy);
    out[0] = (float)elbo;
    out[1] = (float)cc;
}

extern "C" void kernel_launch(void* const* d_in, const int* in_sizes, int n_in,
                              void* d_out, int out_size, void* d_ws, size_t ws_size,
                              hipStream_t stream) {
    const float* I = (const float*)d_in[0];
    const float* SigI = (const float*)d_in[1];
    const int* image_id = (const int*)d_in[2];
    const float* metadata = (const float*)d_in[3];
    const float* wavelength = (const float*)d_in[4];
    const float* dHKL = (const float*)d_in[5];
    const int* refl_ids = (const int*)d_in[6];
    const float* q_loc = (const float*)d_in[7];
    const float* q_scale_raw = (const float*)d_in[8];
    const float* img_emb = (const float*)d_in[9];
    const float* W1 = (const float*)d_in[10];
    const float* b1 = (const float*)d_in[11];
    const float* W2 = (const float*)d_in[12];
    const float* b2 = (const float*)d_in[13];
    const float* zeps = (const float*)d_in[14];
    const float* seps = (const float*)d_in[15];
    float* out = (float*)d_out;

    char* ws = (char*)d_ws;
    double* accs = (double*)ws;                    // [0]=kl [1]=llmax [2..7]=pearson
    float* img_ll_part = (float*)(ws + 64);        // [2000][2][NSLOT]
    int* op_idx = (int*)(ws + 262144);             // [2000]
    float* sqv = (float*)(ws + 524288);            // [250000]
    float* img_pre = (float*)(ws + 1572864);       // [2000][64]
    float* zT = (float*)(ws + 2097152);            // [250000][32]
    float* ipred = (float*)(ws + 34603008);        // [2000000][2]
    float4* params = (float4*)(ws + 52428800);     // [2000000] float4

    hipMemsetAsync(d_ws, 0, 64 + N_IMG_C * 2 * NSLOT * 4, stream);

    k_refl<<<(N_REFL_C + 255) / 256, 256, 0, stream>>>(q_loc, q_scale_raw, zeps,
                                                       sqv, zT, &accs[0]);
    k_imgpre<<<N_IMG_C, 64, 0, stream>>>(img_emb, W1, b1, img_pre);
    k_mlp<<<(N_OBS_C + 511) / 512, 256, 0, stream>>>(I, SigI, image_id, metadata,
                                                     wavelength, dHKL, refl_ids,
                                                     q_loc, W1, W2, b2, sqv,
                                                     img_pre, params);
    k_mc<<<N_OBS_C / 32, 256, 0, stream>>>(I, SigI, image_id, refl_ids,
                                           params, seps, zT, img_ll_part, ipred);
    k_img<<<(N_IMG_C + 255) / 256, 256, 0, stream>>>(img_ll_part, op_idx, &accs[1]);
    k_pearson<<<(N_OBS_C + 255) / 256, 256, 0, stream>>>(I, SigI, image_id, ipred,
                                                         op_idx, &accs[2]);
    k_final<<<1, 1, 0, stream>>>(accs, out);
}

// Round 8
// 268.235 us; speedup vs baseline: 1.3237x; 1.3237x over previous
//
#include <hip/hip_runtime.h>
#include <math.h>

#define N_OBS_C 2000000
#define N_REFL_C 250000
#define N_IMG_C 2000
#define MC_C 32
#define HID 64
#define NSLOT 16
#define LOG2PI_F 1.8378770664093453f

// ---------------- workspace layout (bytes) ----------------
// [0,64)        accs: 8 doubles (kl, llmax, W, Sx, Sy, Sxx, Syy, Sxy)
// [64,1536064)  img_mom [2000][12][NSLOT] float  (zeroed by k_zero)
//               j: 0=ll0 1=ll1 2=w 3=wx 4=wxx 5=wy0 6=wy0y0 7=wxy0
//                  8=wy1 9=wy1y1 10=wxy1 11=pad
// [2097152,..)  sq [250000] float
// [4194304,..)  img_pre [2000][64] float
// [8388608,..)  zT [250000][32] float (32MB)
// [50331648,..) params [2000000] float4 (32MB)

__device__ __forceinline__ float softplusf(float x) {
    return (x > 20.f) ? x : log1pf(expf(x));
}

// ---- K0: zero the accumulator region (replaces hipMemsetAsync) ----
#define ZERO_F4 96004   // (64 + 2000*12*16*4) / 16
__global__ __launch_bounds__(256) void k_zero(float4* __restrict__ p) {
    int i = blockIdx.x * 256 + threadIdx.x;
    if (i < ZERO_F4) p[i] = make_float4(0.f, 0.f, 0.f, 0.f);
}

// ---- K1: per-reflection: sq, KL partial, zT table ----
__global__ __launch_bounds__(256) void k_refl(const float* __restrict__ q_loc,
                                              const float* __restrict__ q_scale_raw,
                                              const float* __restrict__ zeps,
                                              float* __restrict__ sq,
                                              float* __restrict__ zT,
                                              double* __restrict__ kl_sum) {
    int r = blockIdx.x * 256 + threadIdx.x;
    double kl = 0.0;
    if (r < N_REFL_C) {
        float ql = q_loc[r];
        float sp = softplusf(q_scale_raw[r]);
        sq[r] = sp;
        kl = (double)(-logf(sp) + 0.5f * (sp * sp + ql * ql) - 0.5f);
        float z[MC_C];
#pragma unroll
        for (int m = 0; m < MC_C; ++m)
            z[m] = fmaf(sp, zeps[(size_t)m * N_REFL_C + r], ql);
        float4* outp = (float4*)(zT + (size_t)r * MC_C);
#pragma unroll
        for (int q = 0; q < MC_C / 4; ++q)
            outp[q] = make_float4(z[4 * q], z[4 * q + 1], z[4 * q + 2], z[4 * q + 3]);
    }
    for (int o = 32; o > 0; o >>= 1) kl += __shfl_xor(kl, o);
    __shared__ double skl[4];
    int lane = threadIdx.x & 63, w = threadIdx.x >> 6;
    if (lane == 0) skl[w] = kl;
    __syncthreads();
    if (threadIdx.x == 0) atomicAdd(kl_sum, skl[0] + skl[1] + skl[2] + skl[3]);
}

// ---- K1b: per-image precompute ----
__global__ __launch_bounds__(64) void k_imgpre(const float* __restrict__ img_emb,
                                               const float* __restrict__ W1,
                                               const float* __restrict__ b1,
                                               float* __restrict__ img_pre) {
    int g = blockIdx.x;
    int j = threadIdx.x;
    float acc = b1[j];
#pragma unroll
    for (int e = 0; e < 32; ++e)
        acc = fmaf(img_emb[g * 32 + e], W1[(12 + e) * HID + j], acc);
    img_pre[g * HID + j] = acc;
}

// ---- K2a: MLP, 2 obs per thread; weights staged in LDS ----
__global__ __launch_bounds__(256) void k_mlp(const float* __restrict__ I,
                                             const float* __restrict__ SigI,
                                             const int* __restrict__ image_id,
                                             const float* __restrict__ metadata,
                                             const float* __restrict__ wavelength,
                                             const float* __restrict__ dHKL,
                                             const int* __restrict__ refl_ids,
                                             const float* __restrict__ q_loc,
                                             const float* __restrict__ W1,
                                             const float* __restrict__ W2,
                                             const float* __restrict__ b2,
                                             const float* __restrict__ sq,
                                             const float* __restrict__ img_pre,
                                             float4* __restrict__ params) {
    __shared__ float sW1[12 * HID];
    __shared__ float sW2a[HID], sW2b[HID];
    for (int t = threadIdx.x; t < 12 * HID; t += 256) sW1[t] = W1[t];
    if (threadIdx.x < HID) {
        sW2a[threadIdx.x] = W2[threadIdx.x * 2 + 0];
        sW2b[threadIdx.x] = W2[threadIdx.x * 2 + 1];
    }
    __syncthreads();

    int n0 = blockIdx.x * 512 + threadIdx.x;
    int n1 = n0 + 256;
    bool a0 = (n0 < N_OBS_C), a1 = (n1 < N_OBS_C);
    int m0 = a0 ? n0 : (N_OBS_C - 1);
    int m1 = a1 ? n1 : (N_OBS_C - 1);

    float f0[12], f1[12];
    f0[2] = I[m0];   f1[2] = I[m1];
    f0[3] = SigI[m0]; f1[3] = SigI[m1];
#pragma unroll
    for (int i = 0; i < 6; ++i) {
        f0[4 + i] = metadata[(size_t)m0 * 6 + i];
        f1[4 + i] = metadata[(size_t)m1 * 6 + i];
    }
    f0[10] = wavelength[m0]; f1[10] = wavelength[m1];
    float dh0 = dHKL[m0], dh1 = dHKL[m1];
    f0[11] = 1.0f / (dh0 * dh0);
    f1[11] = 1.0f / (dh1 * dh1);
    int g0 = image_id[m0], g1 = image_id[m1];
    int r00 = refl_ids[m0], r01 = refl_ids[N_OBS_C + m0];
    int r10 = refl_ids[m1], r11 = refl_ids[N_OBS_C + m1];
    float qa0 = q_loc[r00], sa0 = sq[r00];
    float qb0 = q_loc[r01], sb0 = sq[r01];
    float qa1 = q_loc[r10], sa1 = sq[r10];
    float qb1 = q_loc[r11], sb1 = sq[r11];
    const float* ip0 = img_pre + (size_t)g0 * HID;
    const float* ip1 = img_pre + (size_t)g1 * HID;

    float bb0 = b2[0], bb1 = b2[1];
    float la00 = bb0, la01 = bb1, lb00 = bb0, lb01 = bb1;
    float la10 = bb0, la11 = bb1, lb10 = bb0, lb11 = bb1;

#pragma unroll 1
    for (int jt = 0; jt < HID; jt += 8) {
        float acc0[8], acc1[8];
        {
            float4 p0a = *(const float4*)&ip0[jt];
            float4 p0b = *(const float4*)&ip0[jt + 4];
            float4 p1a = *(const float4*)&ip1[jt];
            float4 p1b = *(const float4*)&ip1[jt + 4];
            acc0[0] = p0a.x; acc0[1] = p0a.y; acc0[2] = p0a.z; acc0[3] = p0a.w;
            acc0[4] = p0b.x; acc0[5] = p0b.y; acc0[6] = p0b.z; acc0[7] = p0b.w;
            acc1[0] = p1a.x; acc1[1] = p1a.y; acc1[2] = p1a.z; acc1[3] = p1a.w;
            acc1[4] = p1b.x; acc1[5] = p1b.y; acc1[6] = p1b.z; acc1[7] = p1b.w;
        }
#pragma unroll
        for (int i = 2; i < 12; ++i) {
            float4 wa = *(const float4*)&sW1[i * HID + jt];
            float4 wb = *(const float4*)&sW1[i * HID + jt + 4];
            float u0 = f0[i], u1 = f1[i];
            acc0[0] = fmaf(u0, wa.x, acc0[0]); acc1[0] = fmaf(u1, wa.x, acc1[0]);
            acc0[1] = fmaf(u0, wa.y, acc0[1]); acc1[1] = fmaf(u1, wa.y, acc1[1]);
            acc0[2] = fmaf(u0, wa.z, acc0[2]); acc1[2] = fmaf(u1, wa.z, acc1[2]);
            acc0[3] = fmaf(u0, wa.w, acc0[3]); acc1[3] = fmaf(u1, wa.w, acc1[3]);
            acc0[4] = fmaf(u0, wb.x, acc0[4]); acc1[4] = fmaf(u1, wb.x, acc1[4]);
            acc0[5] = fmaf(u0, wb.y, acc0[5]); acc1[5] = fmaf(u1, wb.y, acc1[5]);
            acc0[6] = fmaf(u0, wb.z, acc0[6]); acc1[6] = fmaf(u1, wb.z, acc1[6]);
            acc0[7] = fmaf(u0, wb.w, acc0[7]); acc1[7] = fmaf(u1, wb.w, acc1[7]);
        }
        float4 w0a = *(const float4*)&sW1[jt];
        float4 w0b = *(const float4*)&sW1[jt + 4];
        float4 w1a = *(const float4*)&sW1[HID + jt];
        float4 w1b = *(const float4*)&sW1[HID + jt + 4];
        float w0r[8] = {w0a.x, w0a.y, w0a.z, w0a.w, w0b.x, w0b.y, w0b.z, w0b.w};
        float w1r[8] = {w1a.x, w1a.y, w1a.z, w1a.w, w1b.x, w1b.y, w1b.z, w1b.w};
        float4 va4a = *(const float4*)&sW2a[jt];
        float4 va4b = *(const float4*)&sW2a[jt + 4];
        float4 vb4a = *(const float4*)&sW2b[jt];
        float4 vb4b = *(const float4*)&sW2b[jt + 4];
        float va[8] = {va4a.x, va4a.y, va4a.z, va4a.w, va4b.x, va4b.y, va4b.z, va4b.w};
        float vb[8] = {vb4a.x, vb4a.y, vb4a.z, vb4a.w, vb4b.x, vb4b.y, vb4b.z, vb4b.w};
#pragma unroll
        for (int jj = 0; jj < 8; ++jj) {
            float ha0 = fmaxf(fmaf(qa0, w0r[jj], fmaf(sa0, w1r[jj], acc0[jj])), 0.f);
            la00 = fmaf(ha0, va[jj], la00);
            la01 = fmaf(ha0, vb[jj], la01);
            float hb0 = fmaxf(fmaf(qb0, w0r[jj], fmaf(sb0, w1r[jj], acc0[jj])), 0.f);
            lb00 = fmaf(hb0, va[jj], lb00);
            lb01 = fmaf(hb0, vb[jj], lb01);
            float ha1 = fmaxf(fmaf(qa1, w0r[jj], fmaf(sa1, w1r[jj], acc1[jj])), 0.f);
            la10 = fmaf(ha1, va[jj], la10);
            la11 = fmaf(ha1, vb[jj], la11);
            float hb1 = fmaxf(fmaf(qb1, w0r[jj], fmaf(sb1, w1r[jj], acc1[jj])), 0.f);
            lb10 = fmaf(hb1, va[jj], lb10);
            lb11 = fmaf(hb1, vb[jj], lb11);
        }
    }

    if (a0) params[n0] = make_float4(la00, softplusf(la01), lb00, softplusf(lb01));
    if (a1) params[n1] = make_float4(la10, softplusf(la11), lb10, softplusf(lb11));
}

// ---- K2b: MC likelihood + fused per-image moments; 8 lanes/obs ----
// block 256 = 32 obs; grid = 2M/32 = 62500 exact.
__global__ __launch_bounds__(256) void k_mc(const float* __restrict__ I,
                                            const float* __restrict__ SigI,
                                            const int* __restrict__ image_id,
                                            const int* __restrict__ refl_ids,
                                            const float4* __restrict__ params,
                                            const float* __restrict__ seps,
                                            const float* __restrict__ zT,
                                            float* __restrict__ img_mom) {
    int t = threadIdx.x;
    int grp = t >> 3;            // obs slot in block (0..31)
    int m4 = t & 7;              // sample quartet
    int n = blockIdx.x * 32 + grp;

    float In = I[n];
    float Sn = SigI[n];
    int g = image_id[n];
    int rid0 = refl_ids[n];
    int rid1 = refl_ids[N_OBS_C + n];
    float4 pp = params[n];

    float4 ss = *(const float4*)&seps[(size_t)n * MC_C + m4 * 4];
    float4 z0 = *(const float4*)&zT[(size_t)rid0 * MC_C + m4 * 4];
    float4 z1 = *(const float4*)&zT[(size_t)rid1 * MC_C + m4 * 4];

    float rsig = 1.0f / Sn;
    float mnIr = -In * rsig;

    float sd20 = 0.f, sip0 = 0.f, sd21 = 0.f, sip1 = 0.f;
#define MCSTEP(zc0, zc1, sc_)                              \
    {                                                      \
        float sc0 = fmaf(pp.y, sc_, pp.x);                 \
        float ip0 = zc0 * sc0;                             \
        float d0 = fmaf(ip0, rsig, mnIr);                  \
        sd20 = fmaf(d0, d0, sd20);                         \
        sip0 += ip0;                                       \
        float sc1 = fmaf(pp.w, sc_, pp.z);                 \
        float ip1 = zc1 * sc1;                             \
        float d1 = fmaf(ip1, rsig, mnIr);                  \
        sd21 = fmaf(d1, d1, sd21);                         \
        sip1 += ip1;                                       \
    }
    MCSTEP(z0.x, z1.x, ss.x)
    MCSTEP(z0.y, z1.y, ss.y)
    MCSTEP(z0.z, z1.z, ss.z)
    MCSTEP(z0.w, z1.w, ss.w)
#undef MCSTEP

#pragma unroll
    for (int o = 4; o > 0; o >>= 1) {
        sd20 += __shfl_xor(sd20, o);
        sd21 += __shfl_xor(sd21, o);
        sip0 += __shfl_xor(sip0, o);
        sip1 += __shfl_xor(sip1, o);
    }

    __shared__ float mom[32][12];
    __shared__ int sg[32];
    __shared__ int sameflag;
    if (m4 == 0) {
        float logS32 = 32.f * logf(Sn) + 16.f * LOG2PI_F;
        float y0 = sip0 * (1.0f / 32.0f);
        float y1 = sip1 * (1.0f / 32.0f);
        float w = rsig * rsig;
        mom[grp][0] = -0.5f * sd20 - logS32;
        mom[grp][1] = -0.5f * sd21 - logS32;
        mom[grp][2] = w;
        mom[grp][3] = w * In;
        mom[grp][4] = w * In * In;
        mom[grp][5] = w * y0;
        mom[grp][6] = w * y0 * y0;
        mom[grp][7] = w * In * y0;
        mom[grp][8] = w * y1;
        mom[grp][9] = w * y1 * y1;
        mom[grp][10] = w * In * y1;
        mom[grp][11] = 0.f;
        sg[grp] = g;
    }
    __syncthreads();
    if (t == 0) {
        bool same = true;
        int g0 = sg[0];
#pragma unroll
        for (int s = 1; s < 32; ++s) same = same && (sg[s] == g0);
        sameflag = same;
    }
    __syncthreads();
    int slot = blockIdx.x & (NSLOT - 1);
    if (t < 12) {
        if (sameflag) {
            float a = 0.f;
#pragma unroll
            for (int s = 0; s < 32; ++s) a += mom[s][t];
            atomicAdd(&img_mom[(sg[0] * 12 + t) * NSLOT + slot], a);
        } else {
            for (int s = 0; s < 32; ++s)
                atomicAdd(&img_mom[(sg[s] * 12 + t) * NSLOT + slot], mom[s][t]);
        }
    }
}

// ---- K3: per-image slot-sum + argmax + block-reduced global sums ----
__global__ __launch_bounds__(256) void k_img(const float* __restrict__ img_mom,
                                             double* __restrict__ accs) {
    int g = blockIdx.x * 256 + threadIdx.x;
    double red7[7] = {0, 0, 0, 0, 0, 0, 0};   // llmax, W, Sx, Sy, Sxx, Syy, Sxy
    if (g < N_IMG_C) {
        float M[12];
#pragma unroll
        for (int j = 0; j < 12; ++j) {
            const float4* p = (const float4*)&img_mom[(g * 12 + j) * NSLOT];
            float4 q0 = p[0], q1 = p[1], q2 = p[2], q3 = p[3];
            M[j] = (q0.x + q0.y + q0.z + q0.w) + (q1.x + q1.y + q1.z + q1.w) +
                   (q2.x + q2.y + q2.z + q2.w) + (q3.x + q3.y + q3.z + q3.w);
        }
        float ll0 = M[0] * (1.0f / 32.0f);
        float ll1 = M[1] * (1.0f / 32.0f);
        bool op1 = (ll1 > ll0);
        red7[0] = (double)fmaxf(ll0, ll1);
        red7[1] = (double)M[2];
        red7[2] = (double)M[3];
        red7[3] = (double)(op1 ? M[8] : M[5]);
        red7[4] = (double)M[4];
        red7[5] = (double)(op1 ? M[9] : M[6]);
        red7[6] = (double)(op1 ? M[10] : M[7]);
    }
#pragma unroll
    for (int k = 0; k < 7; ++k)
        for (int o = 32; o > 0; o >>= 1) red7[k] += __shfl_xor(red7[k], o);
    __shared__ double sred[4][7];
    int lane = threadIdx.x & 63, w = threadIdx.x >> 6;
    if (lane == 0) {
#pragma unroll
        for (int k = 0; k < 7; ++k) sred[w][k] = red7[k];
    }
    __syncthreads();
    if (threadIdx.x < 7) {
        double v = sred[0][threadIdx.x] + sred[1][threadIdx.x] +
                   sred[2][threadIdx.x] + sred[3][threadIdx.x];
        atomicAdd(&accs[1 + threadIdx.x], v);
    }
}

// ---- K5: finalize ----
__global__ void k_final(const double* __restrict__ accs, float* __restrict__ out) {
    double kl = accs[0] / (double)N_REFL_C;
    double elbo = -(accs[1] / (double)N_IMG_C) + 1.0 * kl;
    double W = accs[2], Sx = accs[3], Sy = accs[4];
    double Sxx = accs[5], Syy = accs[6], Sxy = accs[7];
    double z = 1.0 / W;
    double mx = z * Sx, my = z * Sy;
    double cxy = z * Sxy - mx * my;
    double cx = z * Sxx - mx * mx;
    double cy = z * Syy - my * my;
    double cc = cxy / sqrt(cx * cy);
    out[0] = (float)elbo;
    out[1] = (float)cc;
}

extern "C" void kernel_launch(void* const* d_in, const int* in_sizes, int n_in,
                              void* d_out, int out_size, void* d_ws, size_t ws_size,
                              hipStream_t stream) {
    const float* I = (const float*)d_in[0];
    const float* SigI = (const float*)d_in[1];
    const int* image_id = (const int*)d_in[2];
    const float* metadata = (const float*)d_in[3];
    const float* wavelength = (const float*)d_in[4];
    const float* dHKL = (const float*)d_in[5];
    const int* refl_ids = (const int*)d_in[6];
    const float* q_loc = (const float*)d_in[7];
    const float* q_scale_raw = (const float*)d_in[8];
    const float* img_emb = (const float*)d_in[9];
    const float* W1 = (const float*)d_in[10];
    const float* b1 = (const float*)d_in[11];
    const float* W2 = (const float*)d_in[12];
    const float* b2 = (const float*)d_in[13];
    const float* zeps = (const float*)d_in[14];
    const float* seps = (const float*)d_in[15];
    float* out = (float*)d_out;

    char* ws = (char*)d_ws;
    double* accs = (double*)ws;                    // 8 doubles
    float* img_mom = (float*)(ws + 64);            // [2000][12][NSLOT]
    float* sqv = (float*)(ws + 2097152);           // [250000]
    float* img_pre = (float*)(ws + 4194304);       // [2000][64]
    float* zT = (float*)(ws + 8388608);            // [250000][32]
    float4* params = (float4*)(ws + 50331648);     // [2000000] float4

    k_zero<<<(ZERO_F4 + 255) / 256, 256, 0, stream>>>((float4*)ws);
    k_refl<<<(N_REFL_C + 255) / 256, 256, 0, stream>>>(q_loc, q_scale_raw, zeps,
                                                       sqv, zT, &accs[0]);
    k_imgpre<<<N_IMG_C, 64, 0, stream>>>(img_emb, W1, b1, img_pre);
    k_mlp<<<(N_OBS_C + 511) / 512, 256, 0, stream>>>(I, SigI, image_id, metadata,
                                                     wavelength, dHKL, refl_ids,
                                                     q_loc, W1, W2, b2, sqv,
                                                     img_pre, params);
    k_mc<<<N_OBS_C / 32, 256, 0, stream>>>(I, SigI, image_id, refl_ids,
                                           params, seps, zT, img_mom);
    k_img<<<(N_IMG_C + 255) / 256, 256, 0, stream>>>(img_mom, accs);
    k_final<<<1, 1, 0, stream>>>(accs, out);
}